// Round 4
// baseline (507.390 us; speedup 1.0000x reference)
//
#include <hip/hip_runtime.h>
#include <hip/hip_bf16.h>

#define D_IN 128
#define F 64   // H1 == H2 == D_OUT == 64
#define NBKT 8

// ============ preprocessing: degree histogram, dinv, scan ============

__global__ __launch_bounds__(256) void hist_kernel(const int* __restrict__ dst,
                                                   int* __restrict__ counts, int E) {
    int e = blockIdx.x * 256 + threadIdx.x;
    if (e < E) atomicAdd(&counts[dst[e]], 1);
}

__global__ __launch_bounds__(256) void dinv_kernel(const int* __restrict__ counts,
                                                   float* __restrict__ dinv, int n) {
    int i = blockIdx.x * 256 + threadIdx.x;
    if (i < n) dinv[i] = rsqrtf((float)counts[i] + 1.0f);
}

__global__ __launch_bounds__(256) void scan1_kernel(const int* __restrict__ counts,
                                                    int* __restrict__ offsets,
                                                    int* __restrict__ bsum, int n) {
    __shared__ int tmp[256];
    int t = threadIdx.x;
    int i = blockIdx.x * 256 + t;
    int v = (i < n) ? counts[i] : 0;
    tmp[t] = v;
    __syncthreads();
    for (int off = 1; off < 256; off <<= 1) {
        int add = (t >= off) ? tmp[t - off] : 0;
        __syncthreads();
        if (t >= off) tmp[t] += add;
        __syncthreads();
    }
    if (i < n) offsets[i] = tmp[t] - v;           // exclusive
    if (t == 255) bsum[blockIdx.x] = tmp[t];      // inclusive block total
}

__global__ __launch_bounds__(1024) void scan2_kernel(int* __restrict__ bsum, int nb) {
    __shared__ int tmp[1024];
    int t = threadIdx.x;
    int v = (t < nb) ? bsum[t] : 0;
    tmp[t] = v;
    __syncthreads();
    for (int off = 1; off < 1024; off <<= 1) {
        int add = (t >= off) ? tmp[t - off] : 0;
        __syncthreads();
        if (t >= off) tmp[t] += add;
        __syncthreads();
    }
    if (t < nb) bsum[t] = tmp[t] - v;             // exclusive
}

__global__ __launch_bounds__(256) void scan3_kernel(int* __restrict__ offsets,
                                                    const int* __restrict__ bsum,
                                                    int* __restrict__ cursors, int n, int E) {
    int i = blockIdx.x * 256 + threadIdx.x;
    if (i < n) {
        int o = offsets[i] + bsum[i >> 8];
        offsets[i] = o;
        cursors[i] = o;
    }
    if (i == 0) offsets[n] = E;
}

// ============ CSR build, phase A: partition edges into 8 dst-range buckets ============
// LDS round-staging: per 256-edge round, bin in LDS, one global atomic per bin to
// reserve space, then bin-contiguous coalesced copy-out of packed (src,dst).
__global__ __launch_bounds__(256) void part_kernel(const int* __restrict__ src,
                                                   const int* __restrict__ dst,
                                                   int E, int bdiv, int cap,
                                                   uint2* __restrict__ ebuf,
                                                   int* __restrict__ bcur) {
    __shared__ int bin_cnt[NBKT], bin_off[NBKT], bin_base[NBKT];
    __shared__ uint2 stage[256];
    const int t = threadIdx.x;

    for (int base = blockIdx.x * 256; base < E; base += gridDim.x * 256) {
        int e = base + t;
        int s = 0, d = 0, bin = -1;
        if (e < E) { s = src[e]; d = dst[e]; bin = d / bdiv; }

        if (t < NBKT) bin_cnt[t] = 0;
        __syncthreads();

        int slot = -1;
        if (bin >= 0) slot = atomicAdd(&bin_cnt[bin], 1);
        __syncthreads();

        if (t == 0) {
            int acc = 0;
#pragma unroll
            for (int k = 0; k < NBKT; ++k) { bin_off[k] = acc; acc += bin_cnt[k]; }
        }
        if (t < NBKT && bin_cnt[t] > 0)
            bin_base[t] = atomicAdd(&bcur[t], bin_cnt[t]);
        __syncthreads();

        if (bin >= 0) stage[bin_off[bin] + slot] = make_uint2((unsigned)s, (unsigned)d);
        __syncthreads();

        int total = bin_off[NBKT - 1] + bin_cnt[NBKT - 1];
        if (t < total) {
            int b2 = 0;
#pragma unroll
            for (int k = 1; k < NBKT; ++k) if (t >= bin_off[k]) b2 = k;
            int pos = bin_base[b2] + (t - bin_off[b2]);
            ebuf[(size_t)b2 * cap + pos] = stage[t];
        }
        __syncthreads();
    }
}

// ============ CSR build, phase B: XCD-local fill ============
// blockIdx%8 == k -> (round-robin) XCD k handles bucket k; its ~820KB csr window
// stays in that XCD's L2 so lines fill before eviction.
__global__ __launch_bounds__(256) void fillb_kernel(const uint2* __restrict__ ebuf,
                                                    const int* __restrict__ bcur, int cap,
                                                    int* __restrict__ cursors,
                                                    int* __restrict__ csr) {
    const int k = blockIdx.x & (NBKT - 1);
    const int cnt = bcur[k];
    const uint2* eb = ebuf + (size_t)k * cap;
    const int stride = (gridDim.x >> 3) * 256;
    for (int i = (blockIdx.x >> 3) * 256 + threadIdx.x; i < cnt; i += stride) {
        uint2 e = eb[i];
        int p = atomicAdd(&cursors[e.y], 1);
        csr[p] = (int)e.x;
    }
}

// ============ GEMM: h2[row] = dinv[row] * (relu?(A[row]) @ W), W is K x 64 ============
// k4 loop unroll CAPPED at 2: full unroll spilled to scratch (R2: 1.7GB traffic).
template<int K, bool RELU_IN>
__global__ __launch_bounds__(256) void gemm_kernel(
        const float* __restrict__ A, const float* __restrict__ W,
        const float* __restrict__ dinv, float* __restrict__ h2, int n) {
    constexpr int F4 = K / 4;
    __shared__ float4 Al[64 * F4];            // swizzled: phys k4 = k4 ^ (rg & 7)
    __shared__ float  Wl[K * F];
    const int t = threadIdx.x;

    for (int i = t; i < K * F / 4; i += 256)
        ((float4*)Wl)[i] = ((const float4*)W)[i];

    const int row0 = blockIdx.x * 64;
    for (int i = t; i < 64 * F4; i += 256) {
        int r = i / F4, k4 = i % F4;
        int gr = row0 + r; if (gr >= n) gr = n - 1;
        float4 v = ((const float4*)(A + (size_t)gr * K))[k4];
        if (RELU_IN) {
            v.x = fmaxf(v.x, 0.f); v.y = fmaxf(v.y, 0.f);
            v.z = fmaxf(v.z, 0.f); v.w = fmaxf(v.w, 0.f);
        }
        Al[r * F4 + (k4 ^ ((r >> 2) & 7))] = v;
    }
    __syncthreads();

    const int rg = t >> 4, cg = t & 15;
    const int r0 = rg * 4, c0 = cg * 4;
    const int sw = rg & 7;

    float acc[4][4] = {};
#pragma unroll 2
    for (int k4 = 0; k4 < F4; ++k4) {
        float4 a[4];
#pragma unroll
        for (int i = 0; i < 4; ++i) a[i] = Al[(r0 + i) * F4 + (k4 ^ sw)];
#pragma unroll
        for (int j = 0; j < 4; ++j) {
            float4 w = *(const float4*)&Wl[(k4 * 4 + j) * F + c0];
#pragma unroll
            for (int i = 0; i < 4; ++i) {
                float av = (j == 0) ? a[i].x : (j == 1) ? a[i].y : (j == 2) ? a[i].z : a[i].w;
                acc[i][0] = fmaf(av, w.x, acc[i][0]);
                acc[i][1] = fmaf(av, w.y, acc[i][1]);
                acc[i][2] = fmaf(av, w.z, acc[i][2]);
                acc[i][3] = fmaf(av, w.w, acc[i][3]);
            }
        }
    }

#pragma unroll
    for (int i = 0; i < 4; ++i) {
        int gr = row0 + r0 + i;
        if (gr < n) {
            float dv = dinv[gr];
            float4 o = make_float4(acc[i][0] * dv, acc[i][1] * dv,
                                   acc[i][2] * dv, acc[i][3] * dv);
            *(float4*)&h2[(size_t)gr * F + c0] = o;
        }
    }
}

// ============ aggregation: out[i] = b + dinv[i] * (h2[i] + sum_{s in in(i)} h2[s]) ============
__global__ __launch_bounds__(256) void agg_kernel(
        const int* __restrict__ offsets, const int* __restrict__ csr,
        const float* __restrict__ dinv, const float* __restrict__ h2,
        const float* __restrict__ b, float* __restrict__ out, int n) {
    int wid  = (int)((blockIdx.x * 256u + threadIdx.x) >> 6);
    int lane = threadIdx.x & 63;
    if (wid >= n) return;

    int beg = offsets[wid], end = offsets[wid + 1];
    float acc = h2[(size_t)wid * F + lane];   // self term

    int j = beg;
    for (; j + 4 <= end; j += 4) {
        int s0 = csr[j], s1 = csr[j + 1], s2 = csr[j + 2], s3 = csr[j + 3];
        float v0 = h2[(size_t)s0 * F + lane];
        float v1 = h2[(size_t)s1 * F + lane];
        float v2 = h2[(size_t)s2 * F + lane];
        float v3 = h2[(size_t)s3 * F + lane];
        acc += v0; acc += v1; acc += v2; acc += v3;
    }
    for (; j < end; ++j) acc += h2[(size_t)csr[j] * F + lane];

    out[(size_t)wid * F + lane] = fmaf(dinv[wid], acc, b[lane]);
}

// ============ launch ============
extern "C" void kernel_launch(void* const* d_in, const int* in_sizes, int n_in,
                              void* d_out, int out_size, void* d_ws, size_t ws_size,
                              hipStream_t stream) {
    const float* x   = (const float*)d_in[0];
    const float* W1  = (const float*)d_in[1];
    const float* b1  = (const float*)d_in[2];
    const float* W2  = (const float*)d_in[3];
    const float* b2  = (const float*)d_in[4];
    const float* W3  = (const float*)d_in[5];
    const float* b3  = (const float*)d_in[6];
    const int*   ei  = (const int*)d_in[7];

    const int n = in_sizes[0] / D_IN;       // 100000
    const int E = in_sizes[7] / 2;          // 1600000
    const int* src = ei;
    const int* dst = ei + E;

    // ---- workspace layout ----
    char* p = (char*)d_ws;
    auto alloc = [&](size_t bytes) { char* q = p; p += (bytes + 255) & ~(size_t)255; return q; };
    int*   counts  = (int*)  alloc((size_t)n * 4);
    int*   offsets = (int*)  alloc((size_t)(n + 1) * 4);
    int*   cursors = (int*)  alloc((size_t)n * 4);
    int*   bsum    = (int*)  alloc(1024 * 4);
    int*   bcur    = (int*)  alloc(256);
    float* dinv    = (float*)alloc((size_t)n * 4);
    int*   csr     = (int*)  alloc((size_t)E * 4);
    float* h2      = (float*)alloc((size_t)n * F * 4);
    float* outA    = (float*)alloc((size_t)n * F * 4);
    float* outF    = (float*)d_out;

    // ebuf aliases the h2/outA region (dead until gemm1; CSR build finishes first)
    uint2* ebuf = (uint2*)h2;
    const int bdiv = (n + NBKT - 1) / NBKT;                 // 12500 nodes/bucket
    const int cap  = E / NBKT + E / 32 + 1024;              // generous headroom

    const int nb      = (n + 255) / 256;
    const int eBlocks = (E + 255) / 256;
    const int gBlocks = (n + 63) / 64;
    const int aBlocks = (int)(((size_t)n * 64 + 255) / 256);

    // ---- degree + CSR build ----
    hipMemsetAsync(counts, 0, (size_t)n * 4, stream);
    hipMemsetAsync(bcur, 0, NBKT * 4, stream);
    hist_kernel <<<eBlocks, 256, 0, stream>>>(dst, counts, E);
    dinv_kernel <<<nb,      256, 0, stream>>>(counts, dinv, n);
    part_kernel <<<512,     256, 0, stream>>>(src, dst, E, bdiv, cap, ebuf, bcur);
    scan1_kernel<<<nb,      256, 0, stream>>>(counts, offsets, bsum, n);
    scan2_kernel<<<1,      1024, 0, stream>>>(bsum, nb);
    scan3_kernel<<<nb,      256, 0, stream>>>(offsets, bsum, cursors, n, E);
    fillb_kernel<<<1024,    256, 0, stream>>>(ebuf, bcur, cap, cursors, csr);

    // ---- layer 1: x (K=128) ----
    gemm_kernel<D_IN, false><<<gBlocks, 256, 0, stream>>>(x, W1, dinv, h2, n);
    agg_kernel<<<aBlocks, 256, 0, stream>>>(offsets, csr, dinv, h2, b1, outA, n);

    // ---- layer 2: relu(outA) (K=64) ----
    gemm_kernel<F, true><<<gBlocks, 256, 0, stream>>>(outA, W2, dinv, h2, n);
    agg_kernel<<<aBlocks, 256, 0, stream>>>(offsets, csr, dinv, h2, b2, outA, n);

    // ---- layer 3: relu(outA) (K=64) ----
    gemm_kernel<F, true><<<gBlocks, 256, 0, stream>>>(outA, W3, dinv, h2, n);
    agg_kernel<<<aBlocks, 256, 0, stream>>>(offsets, csr, dinv, h2, b3, outF, n);
}

// Round 6
// 340.906 us; speedup vs baseline: 1.4884x; 1.4884x over previous
//
#include <hip/hip_runtime.h>
#include <hip/hip_bf16.h>

#define D_IN 128
#define F 64          // H1 == H2 == D_OUT == 64
#define R_EDGES 4096  // edges per partition block

// ===================== radix-16 partition, pass 1 (dst high 4 bits of sub-bucket) ==========
// 4096 edges per block. Per-(wave,bin) LDS counters, one 64-wide shfl scan,
// 16 global atomics per block (space reservation), bin-segmented write.
// Zero per-edge global atomics.
__global__ __launch_bounds__(256) void part1_kernel(
        const int* __restrict__ src, const int* __restrict__ dst, int E,
        unsigned long long M37, int cap1, uint2* __restrict__ ebufB,
        int* __restrict__ bcur1) {
    __shared__ int wcnt[64], incl64[64], cur[64], gbase[16];
    const int t = threadIdx.x, w = t >> 6, lane = t & 63;
    const int base = blockIdx.x * R_EDGES;
    const int lim = min(base + R_EDGES, E);

    if (t < 64) wcnt[t] = 0;
    __syncthreads();

    for (int i = base + t; i < lim; i += 256) {
        int d = dst[i];
        int b = (int)(((unsigned long long)(unsigned)d * M37) >> 37) >> 4;
        atomicAdd(&wcnt[b * 4 + w], 1);
    }
    __syncthreads();

    if (t < 64) {                       // exclusive scan, bin-major index b*4+w
        int v = wcnt[t], x = v;
        for (int dlt = 1; dlt < 64; dlt <<= 1) { int y = __shfl_up(x, dlt); if (lane >= dlt) x += y; }
        incl64[t] = x;
        wcnt[t] = x - v;
    }
    __syncthreads();
    if (t < 16) {
        int T = incl64[t * 4 + 3] - (t ? incl64[t * 4 - 1] : 0);
        gbase[t] = T > 0 ? atomicAdd(&bcur1[t], T) : 0;
    }
    __syncthreads();
    if (t < 64) cur[t] = gbase[t >> 2] + wcnt[t] - wcnt[(t >> 2) << 2];
    __syncthreads();

    for (int i = base + t; i < lim; i += 256) {
        int s = src[i], d = dst[i];
        int b = (int)(((unsigned long long)(unsigned)d * M37) >> 37) >> 4;
        int p = atomicAdd(&cur[b * 4 + w], 1);
        ebufB[(size_t)b * cap1 + p] = make_uint2((unsigned)s, (unsigned)d);
    }
}

// ===================== radix-16 partition, pass 2 (low 4 bits) ==========
#define BPB2 27   // blocks per L1 bucket
__global__ __launch_bounds__(256) void part2_kernel(
        const uint2* __restrict__ ebufB, const int* __restrict__ bcur1,
        unsigned long long M37, int cap1, int cap2,
        uint2* __restrict__ ebufA, int* __restrict__ bcur2) {
    __shared__ int wcnt[64], incl64[64], cur[64], gbase[16];
    const int t = threadIdx.x, w = t >> 6, lane = t & 63;
    const int b1 = blockIdx.x / BPB2, r = blockIdx.x % BPB2;
    const int cnt1 = bcur1[b1];
    const int beg = r * R_EDGES, lim = min(beg + R_EDGES, cnt1);
    if (beg >= cnt1) return;
    const uint2* in = ebufB + (size_t)b1 * cap1;

    if (t < 64) wcnt[t] = 0;
    __syncthreads();

    for (int i = beg + t; i < lim; i += 256) {
        unsigned d = in[i].y;
        int b = (int)(((unsigned long long)d * M37) >> 37) & 15;
        atomicAdd(&wcnt[b * 4 + w], 1);
    }
    __syncthreads();

    if (t < 64) {
        int v = wcnt[t], x = v;
        for (int dlt = 1; dlt < 64; dlt <<= 1) { int y = __shfl_up(x, dlt); if (lane >= dlt) x += y; }
        incl64[t] = x;
        wcnt[t] = x - v;
    }
    __syncthreads();
    if (t < 16) {
        int T = incl64[t * 4 + 3] - (t ? incl64[t * 4 - 1] : 0);
        gbase[t] = T > 0 ? atomicAdd(&bcur2[b1 * 16 + t], T) : 0;
    }
    __syncthreads();
    if (t < 64) cur[t] = gbase[t >> 2] + wcnt[t] - wcnt[(t >> 2) << 2];
    __syncthreads();

    for (int i = beg + t; i < lim; i += 256) {
        uint2 e = in[i];
        int b = (int)(((unsigned long long)e.y * M37) >> 37) & 15;
        int p = atomicAdd(&cur[b * 4 + w], 1);
        ebufA[(size_t)(b1 * 16 + b) * cap2 + p] = e;
    }
}

// ===================== sub-bucket csr base scan + offsets[n] ==========
__global__ __launch_bounds__(256) void scan256_kernel(const int* __restrict__ bcur2,
                                                      int* __restrict__ bbase,
                                                      int* __restrict__ offsets, int n, int E) {
    __shared__ int tmp[256];
    int t = threadIdx.x;
    int v = bcur2[t];
    tmp[t] = v;
    __syncthreads();
    for (int off = 1; off < 256; off <<= 1) {
        int a = (t >= off) ? tmp[t - off] : 0;
        __syncthreads();
        if (t >= off) tmp[t] += a;
        __syncthreads();
    }
    bbase[t] = tmp[t] - v;
    if (t == 0) offsets[n] = E;
}

// ===================== per-sub-bucket sort: counts, scan, csr, offsets, dinv ==========
// One block per sub-bucket (~391 nodes, ~6250 edges). All per-edge atomics are LDS.
__global__ __launch_bounds__(256) void bsort_kernel(
        const uint2* __restrict__ ebufA, const int* __restrict__ bcur2,
        const int* __restrict__ bbase, int cap2, int NPB, int n,
        int* __restrict__ csr, int* __restrict__ offsets, float* __restrict__ dinv) {
    __shared__ int cnt[512], excl[512];
    const int sb = blockIdx.x, t = threadIdx.x;
    const int node0 = sb * NPB;
    const int nn = min(NPB, n - node0);
    if (nn <= 0) return;
    const int cE = bcur2[sb];
    const int base = bbase[sb];
    const uint2* eb = ebufA + (size_t)sb * cap2;

    for (int i = t; i < 512; i += 256) cnt[i] = 0;
    __syncthreads();
    for (int i = t; i < cE; i += 256) atomicAdd(&cnt[eb[i].y - node0], 1);
    __syncthreads();

    if (t < 64) {                         // scan 512 = 8 chunks of 64, wave 0
        int carry = 0;
        for (int c = 0; c < 8; ++c) {
            int v = cnt[c * 64 + t], x = v;
            for (int dlt = 1; dlt < 64; dlt <<= 1) { int y = __shfl_up(x, dlt); if (t >= dlt) x += y; }
            excl[c * 64 + t] = carry + x - v;
            carry += __shfl(x, 63);
        }
    }
    __syncthreads();

    for (int i = t; i < nn; i += 256) {
        offsets[node0 + i] = base + excl[i];
        dinv[node0 + i] = rsqrtf((float)cnt[i] + 1.0f);
    }
    __syncthreads();
    for (int i = t; i < 512; i += 256) cnt[i] = excl[i];   // cursors
    __syncthreads();
    for (int i = t; i < cE; i += 256) {
        uint2 e = eb[i];
        int p = atomicAdd(&cnt[e.y - node0], 1);
        csr[base + p] = (int)e.x;
    }
}

// ============ GEMM: h2[row] = dinv[row] * (relu?(A[row]) @ W), W is K x 64 ============
// k4 loop unroll CAPPED at 2: full unroll spilled to scratch (R2: 1.7GB traffic).
template<int K, bool RELU_IN>
__global__ __launch_bounds__(256) void gemm_kernel(
        const float* __restrict__ A, const float* __restrict__ W,
        const float* __restrict__ dinv, float* __restrict__ h2, int n) {
    constexpr int F4 = K / 4;
    __shared__ float4 Al[64 * F4];            // swizzled: phys k4 = k4 ^ (rg & 7)
    __shared__ float  Wl[K * F];
    const int t = threadIdx.x;

    for (int i = t; i < K * F / 4; i += 256)
        ((float4*)Wl)[i] = ((const float4*)W)[i];

    const int row0 = blockIdx.x * 64;
    for (int i = t; i < 64 * F4; i += 256) {
        int r = i / F4, k4 = i % F4;
        int gr = row0 + r; if (gr >= n) gr = n - 1;
        float4 v = ((const float4*)(A + (size_t)gr * K))[k4];
        if (RELU_IN) {
            v.x = fmaxf(v.x, 0.f); v.y = fmaxf(v.y, 0.f);
            v.z = fmaxf(v.z, 0.f); v.w = fmaxf(v.w, 0.f);
        }
        Al[r * F4 + (k4 ^ ((r >> 2) & 7))] = v;
    }
    __syncthreads();

    const int rg = t >> 4, cg = t & 15;
    const int r0 = rg * 4, c0 = cg * 4;
    const int sw = rg & 7;

    float acc[4][4] = {};
#pragma unroll 2
    for (int k4 = 0; k4 < F4; ++k4) {
        float4 a[4];
#pragma unroll
        for (int i = 0; i < 4; ++i) a[i] = Al[(r0 + i) * F4 + (k4 ^ sw)];
#pragma unroll
        for (int j = 0; j < 4; ++j) {
            float4 w = *(const float4*)&Wl[(k4 * 4 + j) * F + c0];
#pragma unroll
            for (int i = 0; i < 4; ++i) {
                float av = (j == 0) ? a[i].x : (j == 1) ? a[i].y : (j == 2) ? a[i].z : a[i].w;
                acc[i][0] = fmaf(av, w.x, acc[i][0]);
                acc[i][1] = fmaf(av, w.y, acc[i][1]);
                acc[i][2] = fmaf(av, w.z, acc[i][2]);
                acc[i][3] = fmaf(av, w.w, acc[i][3]);
            }
        }
    }

#pragma unroll
    for (int i = 0; i < 4; ++i) {
        int gr = row0 + r0 + i;
        if (gr < n) {
            float dv = dinv[gr];
            float4 o = make_float4(acc[i][0] * dv, acc[i][1] * dv,
                                   acc[i][2] * dv, acc[i][3] * dv);
            *(float4*)&h2[(size_t)gr * F + c0] = o;
        }
    }
}

// ============ aggregation: out[i] = b + dinv[i] * (h2[i] + sum_{s in in(i)} h2[s]) ============
__global__ __launch_bounds__(256) void agg_kernel(
        const int* __restrict__ offsets, const int* __restrict__ csr,
        const float* __restrict__ dinv, const float* __restrict__ h2,
        const float* __restrict__ b, float* __restrict__ out, int n) {
    int wid  = (int)((blockIdx.x * 256u + threadIdx.x) >> 6);
    int lane = threadIdx.x & 63;
    if (wid >= n) return;

    int beg = offsets[wid], end = offsets[wid + 1];
    float acc = h2[(size_t)wid * F + lane];   // self term

    int j = beg;
    for (; j + 4 <= end; j += 4) {
        int s0 = csr[j], s1 = csr[j + 1], s2 = csr[j + 2], s3 = csr[j + 3];
        float v0 = h2[(size_t)s0 * F + lane];
        float v1 = h2[(size_t)s1 * F + lane];
        float v2 = h2[(size_t)s2 * F + lane];
        float v3 = h2[(size_t)s3 * F + lane];
        acc += v0; acc += v1; acc += v2; acc += v3;
    }
    for (; j < end; ++j) acc += h2[(size_t)csr[j] * F + lane];

    out[(size_t)wid * F + lane] = fmaf(dinv[wid], acc, b[lane]);
}

// ============ launch ============
extern "C" void kernel_launch(void* const* d_in, const int* in_sizes, int n_in,
                              void* d_out, int out_size, void* d_ws, size_t ws_size,
                              hipStream_t stream) {
    const float* x   = (const float*)d_in[0];
    const float* W1  = (const float*)d_in[1];
    const float* b1  = (const float*)d_in[2];
    const float* W2  = (const float*)d_in[3];
    const float* b2  = (const float*)d_in[4];
    const float* W3  = (const float*)d_in[5];
    const float* b3  = (const float*)d_in[6];
    const int*   ei  = (const int*)d_in[7];

    const int n = in_sizes[0] / D_IN;       // 100000
    const int E = in_sizes[7] / 2;          // 1600000
    const int* src = ei;
    const int* dst = ei + E;

    const int NPB = (n + 255) >> 8;                          // nodes per sub-bucket (391)
    const unsigned long long M37 = ((1ull << 37) / (unsigned long long)NPB) + 1;
    const int cap1 = E / 16 + 4096;                          // L1 bucket capacity (+13 sigma)
    const int cap2 = 8192;                                   // sub-bucket capacity (+24 sigma)

    // ---- workspace layout ----
    char* p = (char*)d_ws;
    auto alloc = [&](size_t bytes) { char* q = p; p += (bytes + 255) & ~(size_t)255; return q; };
    // bcur1[0:16] and bcur2[0:256] in ONE contiguous alloc so one memset covers both
    // (R5 crash: separate allocs + 256B padding left bcur2 tail poisoned -> OOB writes)
    int*   bcur1   = (int*)  alloc((16 + 256) * 4);
    int*   bcur2   = bcur1 + 16;
    int*   bbase   = (int*)  alloc(256 * 4);
    int*   offsets = (int*)  alloc((size_t)(n + 1) * 4);
    float* dinv    = (float*)alloc((size_t)n * 4);
    int*   csr     = (int*)  alloc((size_t)E * 4);
    float* h2      = (float*)alloc((size_t)n * F * 4);       // 25.6 MB
    float* outA    = (float*)alloc((size_t)n * F * 4);       // 25.6 MB
    float* outF    = (float*)d_out;

    // edge buffers alias the (not-yet-live) h2/outA regions; stream order guarantees
    // ebufB dies before gemm1 writes h2, ebufA dies before agg1 writes outA.
    uint2* ebufB = (uint2*)h2;    // 16  * cap1 * 8B = 13.3 MB <= 25.6 MB
    uint2* ebufA = (uint2*)outA;  // 256 * cap2 * 8B = 16.8 MB <= 25.6 MB

    const int p1Blocks = (E + R_EDGES - 1) / R_EDGES;        // 391
    const int gBlocks  = (n + 63) / 64;
    const int aBlocks  = (int)(((size_t)n * 64 + 255) / 256);

    // ---- CSR build (also produces dinv) ----
    hipMemsetAsync(bcur1, 0, (16 + 256) * 4, stream);
    part1_kernel <<<p1Blocks,  256, 0, stream>>>(src, dst, E, M37, cap1, ebufB, bcur1);
    part2_kernel <<<16 * BPB2, 256, 0, stream>>>(ebufB, bcur1, M37, cap1, cap2, ebufA, bcur2);
    scan256_kernel<<<1,        256, 0, stream>>>(bcur2, bbase, offsets, n, E);
    bsort_kernel <<<256,       256, 0, stream>>>(ebufA, bcur2, bbase, cap2, NPB, n,
                                                 csr, offsets, dinv);

    // ---- layer 1: x (K=128) ----
    gemm_kernel<D_IN, false><<<gBlocks, 256, 0, stream>>>(x, W1, dinv, h2, n);
    agg_kernel<<<aBlocks, 256, 0, stream>>>(offsets, csr, dinv, h2, b1, outA, n);

    // ---- layer 2: relu(outA) (K=64) ----
    gemm_kernel<F, true><<<gBlocks, 256, 0, stream>>>(outA, W2, dinv, h2, n);
    agg_kernel<<<aBlocks, 256, 0, stream>>>(offsets, csr, dinv, h2, b2, outA, n);

    // ---- layer 3: relu(outA) (K=64) ----
    gemm_kernel<F, true><<<gBlocks, 256, 0, stream>>>(outA, W3, dinv, h2, n);
    agg_kernel<<<aBlocks, 256, 0, stream>>>(offsets, csr, dinv, h2, b3, outF, n);
}

// Round 7
// 314.865 us; speedup vs baseline: 1.6115x; 1.0827x over previous
//
#include <hip/hip_runtime.h>
#include <hip/hip_bf16.h>

#define D_IN 128
#define F 64          // H1 == H2 == D_OUT == 64
#define R_EDGES 4096  // edges per partition block

// ===================== radix-16 partition, pass 1 (dst high 4 bits of sub-bucket) ==========
__global__ __launch_bounds__(256) void part1_kernel(
        const int* __restrict__ src, const int* __restrict__ dst, int E,
        unsigned long long M37, int cap1, uint2* __restrict__ ebufB,
        int* __restrict__ bcur1) {
    __shared__ int wcnt[64], incl64[64], cur[64], gbase[16];
    const int t = threadIdx.x, w = t >> 6, lane = t & 63;
    const int base = blockIdx.x * R_EDGES;
    const int lim = min(base + R_EDGES, E);

    if (t < 64) wcnt[t] = 0;
    __syncthreads();

    for (int i = base + t; i < lim; i += 256) {
        int d = dst[i];
        int b = (int)(((unsigned long long)(unsigned)d * M37) >> 37) >> 4;
        atomicAdd(&wcnt[b * 4 + w], 1);
    }
    __syncthreads();

    if (t < 64) {                       // exclusive scan, bin-major index b*4+w
        int v = wcnt[t], x = v;
        for (int dlt = 1; dlt < 64; dlt <<= 1) { int y = __shfl_up(x, dlt); if (lane >= dlt) x += y; }
        incl64[t] = x;
        wcnt[t] = x - v;
    }
    __syncthreads();
    if (t < 16) {
        int T = incl64[t * 4 + 3] - (t ? incl64[t * 4 - 1] : 0);
        gbase[t] = T > 0 ? atomicAdd(&bcur1[t], T) : 0;
    }
    __syncthreads();
    if (t < 64) cur[t] = gbase[t >> 2] + wcnt[t] - wcnt[(t >> 2) << 2];
    __syncthreads();

    for (int i = base + t; i < lim; i += 256) {
        int s = src[i], d = dst[i];
        int b = (int)(((unsigned long long)(unsigned)d * M37) >> 37) >> 4;
        int p = atomicAdd(&cur[b * 4 + w], 1);
        ebufB[(size_t)b * cap1 + p] = make_uint2((unsigned)s, (unsigned)d);
    }
}

// ===================== radix-16 partition, pass 2 (low 4 bits) ==========
#define BPB2 27   // blocks per L1 bucket
__global__ __launch_bounds__(256) void part2_kernel(
        const uint2* __restrict__ ebufB, const int* __restrict__ bcur1,
        unsigned long long M37, int cap1, int cap2,
        uint2* __restrict__ ebufA, int* __restrict__ bcur2) {
    __shared__ int wcnt[64], incl64[64], cur[64], gbase[16];
    const int t = threadIdx.x, w = t >> 6, lane = t & 63;
    const int b1 = blockIdx.x / BPB2, r = blockIdx.x % BPB2;
    const int cnt1 = bcur1[b1];
    const int beg = r * R_EDGES, lim = min(beg + R_EDGES, cnt1);
    if (beg >= cnt1) return;
    const uint2* in = ebufB + (size_t)b1 * cap1;

    if (t < 64) wcnt[t] = 0;
    __syncthreads();

    for (int i = beg + t; i < lim; i += 256) {
        unsigned d = in[i].y;
        int b = (int)(((unsigned long long)d * M37) >> 37) & 15;
        atomicAdd(&wcnt[b * 4 + w], 1);
    }
    __syncthreads();

    if (t < 64) {
        int v = wcnt[t], x = v;
        for (int dlt = 1; dlt < 64; dlt <<= 1) { int y = __shfl_up(x, dlt); if (lane >= dlt) x += y; }
        incl64[t] = x;
        wcnt[t] = x - v;
    }
    __syncthreads();
    if (t < 16) {
        int T = incl64[t * 4 + 3] - (t ? incl64[t * 4 - 1] : 0);
        gbase[t] = T > 0 ? atomicAdd(&bcur2[b1 * 16 + t], T) : 0;
    }
    __syncthreads();
    if (t < 64) cur[t] = gbase[t >> 2] + wcnt[t] - wcnt[(t >> 2) << 2];
    __syncthreads();

    for (int i = beg + t; i < lim; i += 256) {
        uint2 e = in[i];
        int b = (int)(((unsigned long long)e.y * M37) >> 37) & 15;
        int p = atomicAdd(&cur[b * 4 + w], 1);
        ebufA[(size_t)(b1 * 16 + b) * cap2 + p] = e;
    }
}

// ===================== sub-bucket csr base scan + offsets[n] ==========
__global__ __launch_bounds__(256) void scan256_kernel(const int* __restrict__ bcur2,
                                                      int* __restrict__ bbase,
                                                      int* __restrict__ offsets, int n, int E) {
    __shared__ int tmp[256];
    int t = threadIdx.x;
    int v = bcur2[t];
    tmp[t] = v;
    __syncthreads();
    for (int off = 1; off < 256; off <<= 1) {
        int a = (t >= off) ? tmp[t - off] : 0;
        __syncthreads();
        if (t >= off) tmp[t] += a;
        __syncthreads();
    }
    bbase[t] = tmp[t] - v;
    if (t == 0) offsets[n] = E;
}

// ===================== per-sub-bucket sort: counts, scan, csr, offsets, dinv ==========
__global__ __launch_bounds__(256) void bsort_kernel(
        const uint2* __restrict__ ebufA, const int* __restrict__ bcur2,
        const int* __restrict__ bbase, int cap2, int NPB, int n,
        int* __restrict__ csr, int* __restrict__ offsets, float* __restrict__ dinv) {
    __shared__ int cnt[512], excl[512];
    const int sb = blockIdx.x, t = threadIdx.x;
    const int node0 = sb * NPB;
    const int nn = min(NPB, n - node0);
    if (nn <= 0) return;
    const int cE = bcur2[sb];
    const int base = bbase[sb];
    const uint2* eb = ebufA + (size_t)sb * cap2;

    for (int i = t; i < 512; i += 256) cnt[i] = 0;
    __syncthreads();
    for (int i = t; i < cE; i += 256) atomicAdd(&cnt[eb[i].y - node0], 1);
    __syncthreads();

    if (t < 64) {                         // scan 512 = 8 chunks of 64, wave 0
        int carry = 0;
        for (int c = 0; c < 8; ++c) {
            int v = cnt[c * 64 + t], x = v;
            for (int dlt = 1; dlt < 64; dlt <<= 1) { int y = __shfl_up(x, dlt); if (t >= dlt) x += y; }
            excl[c * 64 + t] = carry + x - v;
            carry += __shfl(x, 63);
        }
    }
    __syncthreads();

    for (int i = t; i < nn; i += 256) {
        offsets[node0 + i] = base + excl[i];
        dinv[node0 + i] = rsqrtf((float)cnt[i] + 1.0f);
    }
    __syncthreads();
    for (int i = t; i < 512; i += 256) cnt[i] = excl[i];   // cursors
    __syncthreads();
    for (int i = t; i < cE; i += 256) {
        uint2 e = eb[i];
        int p = atomicAdd(&cnt[e.y - node0], 1);
        csr[base + p] = (int)e.x;
    }
}

// ============ GEMM: h2[row] = dinv[row] * (relu?(A[row]) @ W), W is K x 64 ============
// k4 loop unroll CAPPED at 2: full unroll spilled to scratch (R2: 1.7GB traffic).
template<int K, bool RELU_IN>
__global__ __launch_bounds__(256) void gemm_kernel(
        const float* __restrict__ A, const float* __restrict__ W,
        const float* __restrict__ dinv, float* __restrict__ h2, int n) {
    constexpr int F4 = K / 4;
    __shared__ float4 Al[64 * F4];            // swizzled: phys k4 = k4 ^ (rg & 7)
    __shared__ float  Wl[K * F];
    const int t = threadIdx.x;

    for (int i = t; i < K * F / 4; i += 256)
        ((float4*)Wl)[i] = ((const float4*)W)[i];

    const int row0 = blockIdx.x * 64;
    for (int i = t; i < 64 * F4; i += 256) {
        int r = i / F4, k4 = i % F4;
        int gr = row0 + r; if (gr >= n) gr = n - 1;
        float4 v = ((const float4*)(A + (size_t)gr * K))[k4];
        if (RELU_IN) {
            v.x = fmaxf(v.x, 0.f); v.y = fmaxf(v.y, 0.f);
            v.z = fmaxf(v.z, 0.f); v.w = fmaxf(v.w, 0.f);
        }
        Al[r * F4 + (k4 ^ ((r >> 2) & 7))] = v;
    }
    __syncthreads();

    const int rg = t >> 4, cg = t & 15;
    const int r0 = rg * 4, c0 = cg * 4;
    const int sw = rg & 7;

    float acc[4][4] = {};
#pragma unroll 2
    for (int k4 = 0; k4 < F4; ++k4) {
        float4 a[4];
#pragma unroll
        for (int i = 0; i < 4; ++i) a[i] = Al[(r0 + i) * F4 + (k4 ^ sw)];
#pragma unroll
        for (int j = 0; j < 4; ++j) {
            float4 w = *(const float4*)&Wl[(k4 * 4 + j) * F + c0];
#pragma unroll
            for (int i = 0; i < 4; ++i) {
                float av = (j == 0) ? a[i].x : (j == 1) ? a[i].y : (j == 2) ? a[i].z : a[i].w;
                acc[i][0] = fmaf(av, w.x, acc[i][0]);
                acc[i][1] = fmaf(av, w.y, acc[i][1]);
                acc[i][2] = fmaf(av, w.z, acc[i][2]);
                acc[i][3] = fmaf(av, w.w, acc[i][3]);
            }
        }
    }

#pragma unroll
    for (int i = 0; i < 4; ++i) {
        int gr = row0 + r0 + i;
        if (gr < n) {
            float dv = dinv[gr];
            float4 o = make_float4(acc[i][0] * dv, acc[i][1] * dv,
                                   acc[i][2] * dv, acc[i][3] * dv);
            *(float4*)&h2[(size_t)gr * F + c0] = o;
        }
    }
}

// ============ aggregation: out[i] = b + dinv[i] * (h2[i] + sum_{s in in(i)} h2[s]) ============
// One wave per node. Lane = (edge-slot g in 0..3, feature-quad q in 0..15): each lane
// gathers float4, so 4 edges' 256B rows are in flight per instruction (+2x unroll = 8).
// Cross-slot reduce via shfl_xor(16,32); lanes g==0 store the 256B output row.
__global__ __launch_bounds__(256) void agg_kernel(
        const int* __restrict__ offsets, const int* __restrict__ csr,
        const float* __restrict__ dinv, const float* __restrict__ h2,
        const float* __restrict__ bvec, float* __restrict__ out, int n) {
    const int wid  = (int)((blockIdx.x * 256u + threadIdx.x) >> 6);
    const int lane = threadIdx.x & 63;
    const int g = lane >> 4, q = lane & 15;
    if (wid >= n) return;

    const int beg = offsets[wid], end = offsets[wid + 1];

    float4 acc = make_float4(0.f, 0.f, 0.f, 0.f);
    if (g == 0) acc = *(const float4*)&h2[(size_t)wid * F + q * 4];   // self term

    int j = beg + g;
    for (; j + 4 < end; j += 8) {                 // 8 gathers in flight per wave
        int s0 = csr[j], s1 = csr[j + 4];
        float4 v0 = *(const float4*)&h2[(size_t)s0 * F + q * 4];
        float4 v1 = *(const float4*)&h2[(size_t)s1 * F + q * 4];
        acc.x += v0.x + v1.x; acc.y += v0.y + v1.y;
        acc.z += v0.z + v1.z; acc.w += v0.w + v1.w;
    }
    if (j < end) {
        int s0 = csr[j];
        float4 v0 = *(const float4*)&h2[(size_t)s0 * F + q * 4];
        acc.x += v0.x; acc.y += v0.y; acc.z += v0.z; acc.w += v0.w;
    }

    // reduce across the 4 edge-slots
    acc.x += __shfl_xor(acc.x, 16); acc.y += __shfl_xor(acc.y, 16);
    acc.z += __shfl_xor(acc.z, 16); acc.w += __shfl_xor(acc.w, 16);
    acc.x += __shfl_xor(acc.x, 32); acc.y += __shfl_xor(acc.y, 32);
    acc.z += __shfl_xor(acc.z, 32); acc.w += __shfl_xor(acc.w, 32);

    if (g == 0) {
        float dv = dinv[wid];
        float4 bb = *(const float4*)&bvec[q * 4];
        float4 o = make_float4(fmaf(dv, acc.x, bb.x), fmaf(dv, acc.y, bb.y),
                               fmaf(dv, acc.z, bb.z), fmaf(dv, acc.w, bb.w));
        *(float4*)&out[(size_t)wid * F + q * 4] = o;
    }
}

// ============ launch ============
extern "C" void kernel_launch(void* const* d_in, const int* in_sizes, int n_in,
                              void* d_out, int out_size, void* d_ws, size_t ws_size,
                              hipStream_t stream) {
    const float* x   = (const float*)d_in[0];
    const float* W1  = (const float*)d_in[1];
    const float* b1  = (const float*)d_in[2];
    const float* W2  = (const float*)d_in[3];
    const float* b2  = (const float*)d_in[4];
    const float* W3  = (const float*)d_in[5];
    const float* b3  = (const float*)d_in[6];
    const int*   ei  = (const int*)d_in[7];

    const int n = in_sizes[0] / D_IN;       // 100000
    const int E = in_sizes[7] / 2;          // 1600000
    const int* src = ei;
    const int* dst = ei + E;

    const int NPB = (n + 255) >> 8;                          // nodes per sub-bucket (391)
    const unsigned long long M37 = ((1ull << 37) / (unsigned long long)NPB) + 1;
    const int cap1 = E / 16 + 4096;                          // L1 bucket capacity (+13 sigma)
    const int cap2 = 8192;                                   // sub-bucket capacity (+24 sigma)

    // ---- workspace layout ----
    char* p = (char*)d_ws;
    auto alloc = [&](size_t bytes) { char* q = p; p += (bytes + 255) & ~(size_t)255; return q; };
    // bcur1[0:16] and bcur2[0:256] in ONE contiguous alloc so one memset covers both
    int*   bcur1   = (int*)  alloc((16 + 256) * 4);
    int*   bcur2   = bcur1 + 16;
    int*   bbase   = (int*)  alloc(256 * 4);
    int*   offsets = (int*)  alloc((size_t)(n + 1) * 4);
    float* dinv    = (float*)alloc((size_t)n * 4);
    int*   csr     = (int*)  alloc((size_t)E * 4);
    float* h2      = (float*)alloc((size_t)n * F * 4);       // 25.6 MB
    float* outA    = (float*)alloc((size_t)n * F * 4);       // 25.6 MB
    float* outF    = (float*)d_out;

    // edge buffers alias the (not-yet-live) h2/outA regions
    uint2* ebufB = (uint2*)h2;    // 16  * cap1 * 8B = 13.3 MB <= 25.6 MB
    uint2* ebufA = (uint2*)outA;  // 256 * cap2 * 8B = 16.8 MB <= 25.6 MB

    const int p1Blocks = (E + R_EDGES - 1) / R_EDGES;        // 391
    const int gBlocks  = (n + 63) / 64;
    const int aBlocks  = (int)(((size_t)n * 64 + 255) / 256);

    // ---- CSR build (also produces dinv) ----
    hipMemsetAsync(bcur1, 0, (16 + 256) * 4, stream);
    part1_kernel <<<p1Blocks,  256, 0, stream>>>(src, dst, E, M37, cap1, ebufB, bcur1);
    part2_kernel <<<16 * BPB2, 256, 0, stream>>>(ebufB, bcur1, M37, cap1, cap2, ebufA, bcur2);
    scan256_kernel<<<1,        256, 0, stream>>>(bcur2, bbase, offsets, n, E);
    bsort_kernel <<<256,       256, 0, stream>>>(ebufA, bcur2, bbase, cap2, NPB, n,
                                                 csr, offsets, dinv);

    // ---- layer 1: x (K=128) ----
    gemm_kernel<D_IN, false><<<gBlocks, 256, 0, stream>>>(x, W1, dinv, h2, n);
    agg_kernel<<<aBlocks, 256, 0, stream>>>(offsets, csr, dinv, h2, b1, outA, n);

    // ---- layer 2: relu(outA) (K=64) ----
    gemm_kernel<F, true><<<gBlocks, 256, 0, stream>>>(outA, W2, dinv, h2, n);
    agg_kernel<<<aBlocks, 256, 0, stream>>>(offsets, csr, dinv, h2, b2, outA, n);

    // ---- layer 3: relu(outA) (K=64) ----
    gemm_kernel<F, true><<<gBlocks, 256, 0, stream>>>(outA, W3, dinv, h2, n);
    agg_kernel<<<aBlocks, 256, 0, stream>>>(offsets, csr, dinv, h2, b3, outF, n);
}